// Round 2
// baseline (3626.831 us; speedup 1.0000x reference)
//
#include <hip/hip_runtime.h>
#include <stdint.h>

// Problem constants
#define NSC 64
#define NVC 32
#define DIMF 160
#define LATD 128
#define HIDD 256
#define N_EDGES_K 300000
#define N_ACT_K 200000
#define NE_TILE 8

typedef unsigned short u16;

__device__ __forceinline__ float b2f(u16 x) {
    union { unsigned int u; float f; } v; v.u = ((unsigned int)x) << 16; return v.f;
}
__device__ __forceinline__ u16 f2b(float f) {
    union { unsigned int u; float f; } v; v.f = f;
    return (u16)((v.u + 0x7fffu + ((v.u >> 16) & 1u)) >> 16);
}

// F32=1: buffers are float32.  F32=0: buffers are bf16 (u16).
template<int F32>
__device__ __forceinline__ float ldx(const void* p, size_t i) {
    if (F32) return ((const float*)p)[i];
    return b2f(((const u16*)p)[i]);
}
template<int F32>
__device__ __forceinline__ void stx(void* p, size_t i, float v) {
    if (!(fabsf(v) < 1e30f)) v = 12345.0f;  // diagnostic sentinel: NaN/inf -> visible finite
    if (F32) ((float*)p)[i] = v;
    else     ((u16*)p)[i] = f2b(v);
}

__device__ __forceinline__ float wsum(float v) {
#pragma unroll
    for (int m = 32; m > 0; m >>= 1) v += __shfl_xor(v, m, 64);
    return v;
}
__device__ __forceinline__ float fsig(float x)  { return 1.f / (1.f + __expf(-x)); }
__device__ __forceinline__ float fsilu(float x) { return x / (1.f + __expf(-x)); }

// Normalize one DIM=160 row (64 scalars layernorm + 32 3-vectors rmsnorm), wave-cooperative.
template<int F32>
__device__ __forceinline__ void norm_row(const void* __restrict__ row, size_t off,
                                         const void* __restrict__ gs,
                                         const void* __restrict__ bs,
                                         const void* __restrict__ gv,
                                         float* ds, float* dv, int lane) {
    float s  = ldx<F32>(row, off + lane);
    float va = ldx<F32>(row, off + 64 + lane);
    float vb = (lane < 32) ? ldx<F32>(row, off + 128 + lane) : 0.f;
    float mu  = wsum(s) * (1.f / 64.f);
    float var = wsum(s * s) * (1.f / 64.f) - mu * mu;
    float n2  = wsum(va * va + vb * vb);
    float invs = rsqrtf(var + 1e-5f);
    float invv = rsqrtf(n2 * (1.f / 32.f) + 1e-5f);
    ds[lane] = (s - mu) * invs * ldx<F32>(gs, lane) + ldx<F32>(bs, lane);
    dv[lane] = va * invv * ldx<F32>(gv, lane / 3);
    if (lane < 32) dv[64 + lane] = vb * invv * ldx<F32>(gv, (64 + lane) / 3);
}

// Detect input dtype: read 256 u16 from node_features (pure N(0,1) data).
// bf16 data -> ~100% sane exponents; f32 data read as u16 pairs -> ~59% sane.
__global__ void detect_kernel(const u16* __restrict__ probe, int* __restrict__ flag) {
    __shared__ int cnt;
    if (threadIdx.x == 0) cnt = 0;
    __syncthreads();
    u16 x = probe[threadIdx.x];
    int e = (x >> 7) & 0xFF;
    int sane = ((x & 0x7FFF) == 0) || (e >= 96 && e <= 143);
    atomicAdd(&cnt, sane);
    __syncthreads();
    if (threadIdx.x == 0) *flag = (cnt >= 240) ? 0 : 1;  // 0 = bf16, 1 = f32
}

template<int F32>
__global__ void copy_lat_kernel(const int* __restrict__ flag,
                                const uint4* __restrict__ in, uint4* __restrict__ out, int n) {
    if (*flag != F32) return;
    int i = blockIdx.x * blockDim.x + threadIdx.x;
    if (i < n) out[i] = in[i];
}

template<int F32>
__global__ __launch_bounds__(256, 3)
void edge_kernel(const int* __restrict__ flag,
                 const void* __restrict__ latents,
                 const void* __restrict__ nodef,
                 const void* __restrict__ onehot,
                 const void* __restrict__ edgef,
                 const void* __restrict__ esh,
                 const int* __restrict__ eidx,
                 const void* __restrict__ cutc,
                 const int* __restrict__ act,
                 const void* __restrict__ n_gs, const void* __restrict__ n_bs, const void* __restrict__ n_gv,
                 const void* __restrict__ e_gs, const void* __restrict__ e_bs, const void* __restrict__ e_gv,
                 const void* __restrict__ lg, const void* __restrict__ lb,
                 const void* __restrict__ Wa, const void* __restrict__ Wb,
                 const void* __restrict__ Wc, const void* __restrict__ Wd,
                 const void* __restrict__ Wps, const void* __restrict__ Wpv,
                 const void* __restrict__ Wedge, const void* __restrict__ Wl1,
                 const void* __restrict__ Wl2, const void* __restrict__ Wrs,
                 const void* __restrict__ Wrv,
                 void* __restrict__ out_edge, void* __restrict__ out_lat)
{
    if (*flag != F32) return;

    // arena: cols 0..191 = s_all (later lat_in 0..231), 192..287 = t2
    __shared__ float arena[NE_TILE][288];
    // vall: 96 vectors x 3 comps (idx 3v+c); later reused for raw edge features (160)
    __shared__ float vall[NE_TILE][288];
    __shared__ float osb [NE_TILE][96];
    __shared__ float latb[NE_TILE][128];
    __shared__ float latn[NE_TILE][128];
    __shared__ float wwb [NE_TILE][96];
    __shared__ float mspb[NE_TILE][64];
    __shared__ float mvpb[NE_TILE][96];
    __shared__ float msvb[NE_TILE][160];   // m_s (64) then m_v (96, idx 3w+c)
    __shared__ float hidb[NE_TILE][256];   // early: sWc (0..31) + vWd (32..127); late: hid
    __shared__ float shb [NE_TILE][4];
    __shared__ float ohib[NE_TILE][4];
    __shared__ float ohjb[NE_TILE][4];
    __shared__ float cutb[NE_TILE];
    __shared__ int   aib [NE_TILE];

    const int tid  = threadIdx.x;
    const int wid  = tid >> 6;
    const int lane = tid & 63;
    const int base = blockIdx.x * NE_TILE;

    // ---- Phase A: load + normalize (one wave per edge) ----
    for (int t = wid; t < NE_TILE; t += 4) {
        const int E = base + t;
        const int a = act[E];
        const int i = eidx[a];
        const int j = eidx[N_EDGES_K + a];
        norm_row<F32>(nodef, (size_t)i * DIMF, n_gs, n_bs, n_gv, &arena[t][0],   &vall[t][0],   lane);
        norm_row<F32>(edgef, (size_t)E * DIMF, e_gs, e_bs, e_gv, &arena[t][64],  &vall[t][96],  lane);
        norm_row<F32>(nodef, (size_t)j * DIMF, n_gs, n_bs, n_gv, &arena[t][128], &vall[t][192], lane);
        float x0 = ldx<F32>(latents, (size_t)a * LATD + lane);
        float x1 = ldx<F32>(latents, (size_t)a * LATD + 64 + lane);
        float mu  = wsum(x0 + x1) * (1.f / 128.f);
        float var = wsum(x0 * x0 + x1 * x1) * (1.f / 128.f) - mu * mu;
        float inv = rsqrtf(var + 1e-5f);
        latb[t][lane]      = x0;
        latb[t][64 + lane] = x1;
        latn[t][lane]      = (x0 - mu) * inv * ldx<F32>(lg, lane)      + ldx<F32>(lb, lane);
        latn[t][64 + lane] = (x1 - mu) * inv * ldx<F32>(lg, 64 + lane) + ldx<F32>(lb, 64 + lane);
        if (lane < 4) {
            shb [t][lane] = ldx<F32>(esh, (size_t)E * 4 + lane);
            ohib[t][lane] = ldx<F32>(onehot, (size_t)i * 4 + lane);
            ohjb[t][lane] = ldx<F32>(onehot, (size_t)j * 4 + lane);
        }
        if (lane == 0) { cutb[t] = ldx<F32>(cutc, a); aib[t] = a; }
    }
    __syncthreads();

    // ---- t2[v] = (v_all . sh1) / sqrt(3) ----
    for (int idx = tid; idx < NE_TILE * 96; idx += 256) {
        int t = idx / 96, v = idx % 96;
        arena[t][192 + v] = (vall[t][3*v] * shb[t][1] + vall[t][3*v+1] * shb[t][2] +
                             vall[t][3*v+2] * shb[t][3]) * 0.5773502691896258f;
    }
    __syncthreads();

    // ---- C1: sWc = s_all @ Wc (K=192,OUT=32) ; C2: vWd (K=96 over v, OUT=32, 3 comps) ----
    {
        int o = tid & 31, t = tid >> 5;
        float acc = 0.f;
#pragma unroll 4
        for (int k = 0; k < 192; ++k) acc += ldx<F32>(Wc, k * 32 + o) * arena[t][k];
        hidb[t][o] = acc;
        float a0 = 0.f, a1 = 0.f, a2 = 0.f;
#pragma unroll 4
        for (int v = 0; v < 96; ++v) {
            float w = ldx<F32>(Wd, v * 32 + o);
            a0 += w * vall[t][3*v];
            a1 += w * vall[t][3*v+1];
            a2 += w * vall[t][3*v+2];
        }
        hidb[t][32 + 3*o    ] = a0;
        hidb[t][32 + 3*o + 1] = a1;
        hidb[t][32 + 3*o + 2] = a2;
    }
    __syncthreads();

    // ---- scale s_all by sh0 in place ----
    for (int idx = tid; idx < NE_TILE * 192; idx += 256) {
        int t = idx / 192, k = idx % 192;
        arena[t][k] *= shb[t][0];
    }
    __syncthreads();

    // ---- B: o_s = [s_all*sh0 ; t2] @ [Wa;Wb]  (K=288, OUT=96) ----
    {
        int o = tid % 96, g = tid / 96;
        if (g < 2) {
            int t0 = g * 4;
            float acc[4] = {0, 0, 0, 0};
#pragma unroll 2
            for (int k = 0; k < 192; ++k) {
                float w = ldx<F32>(Wa, k * 96 + o);
#pragma unroll
                for (int e = 0; e < 4; ++e) acc[e] += w * arena[t0 + e][k];
            }
#pragma unroll 2
            for (int k = 0; k < 96; ++k) {
                float w = ldx<F32>(Wb, k * 96 + o);
#pragma unroll
                for (int e = 0; e < 4; ++e) acc[e] += w * arena[t0 + e][192 + k];
            }
#pragma unroll
            for (int e = 0; e < 4; ++e) osb[t0 + e][o] = acc[e];
        }
    }
    __syncthreads();

    // ---- elementwise: m_v_pre, m_s_pre, lat_in build, raw edge-feature reload ----
    for (int idx = tid; idx < NE_TILE * 96; idx += 256) {
        int t = idx / 96, r = idx % 96, o = r / 3, c = r % 3;
        float sc = hidb[t][o];
        float wd = hidb[t][32 + r];
        mvpb[t][r] = (sc * shb[t][1 + c] + wd * shb[t][0]) * fsig(osb[t][64 + o]);
    }
    for (int idx = tid; idx < NE_TILE * 64; idx += 256) {
        int t = idx >> 6, o = idx & 63;
        mspb[t][o] = fsilu(osb[t][o]);
    }
    for (int idx = tid; idx < NE_TILE * 232; idx += 256) {
        int t = idx / 232, k = idx % 232;
        float v;
        if (k < 4)        v = ohib[t][k];
        else if (k < 132) v = latn[t][k - 4];
        else if (k < 228) v = osb[t][k - 132];
        else              v = ohjb[t][k - 228];
        arena[t][k] = v;
    }
    for (int idx = tid; idx < NE_TILE * 160; idx += 256) {
        int t = idx / 160, d = idx % 160;
        vall[t][d] = ldx<F32>(edgef, (size_t)(base + t) * DIMF + d);
    }
    __syncthreads();

    // ---- D1: m_s = silu(o_s) @ Wp_s (K=64,OUT=64) ; D2: m_v (K=32,OUT=32,3c) ----
    {
        int o = tid & 63, g = tid >> 6;
        int t0 = g * 2;
        float acc0 = 0.f, acc1 = 0.f;
#pragma unroll 4
        for (int k = 0; k < 64; ++k) {
            float w = ldx<F32>(Wps, k * 64 + o);
            acc0 += w * mspb[t0][k];
            acc1 += w * mspb[t0 + 1][k];
        }
        msvb[t0][o]     = acc0;
        msvb[t0 + 1][o] = acc1;
        int o2 = tid & 31, t = tid >> 5;
        float a0 = 0.f, a1 = 0.f, a2 = 0.f;
#pragma unroll 4
        for (int v = 0; v < 32; ++v) {
            float w = ldx<F32>(Wpv, v * 32 + o2);
            a0 += w * mvpb[t][3*v];
            a1 += w * mvpb[t][3*v+1];
            a2 += w * mvpb[t][3*v+2];
        }
        msvb[t][64 + 3*o2    ] = a0;
        msvb[t][64 + 3*o2 + 1] = a1;
        msvb[t][64 + 3*o2 + 2] = a2;
    }
    // ---- E: ww = lat @ W_edge (K=128, OUT=96) ----
    {
        int o = tid % 96, g = tid / 96;
        if (g < 2) {
            int t0 = g * 4;
            float acc[4] = {0, 0, 0, 0};
#pragma unroll 2
            for (int k = 0; k < 128; ++k) {
                float w = ldx<F32>(Wedge, k * 96 + o);
#pragma unroll
                for (int e = 0; e < 4; ++e) acc[e] += w * latb[t0 + e][k];
            }
#pragma unroll
            for (int e = 0; e < 4; ++e) wwb[t0 + e][o] = acc[e];
        }
    }
    // ---- F1: hid = silu(lat_in @ W_lat1)  (K=232, OUT=256) ----
    {
        int o = tid;
        float acc[NE_TILE] = {0, 0, 0, 0, 0, 0, 0, 0};
#pragma unroll 2
        for (int k = 0; k < 232; ++k) {
            float w = ldx<F32>(Wl1, k * 256 + o);
#pragma unroll
            for (int e = 0; e < NE_TILE; ++e) acc[e] += w * arena[e][k];
        }
#pragma unroll
        for (int e = 0; e < NE_TILE; ++e) hidb[e][o] = fsilu(acc[e]);
    }
    __syncthreads();

    // ---- F2: new_lat = (hid @ W_lat2) * cutoff  (K=256, OUT=128) ----
    {
        int o = tid & 127, g = tid >> 7;
        int t0 = g * 4;
        float acc[4] = {0, 0, 0, 0};
#pragma unroll 2
        for (int k = 0; k < 256; ++k) {
            float w = ldx<F32>(Wl2, k * 128 + o);
#pragma unroll
            for (int e = 0; e < 4; ++e) acc[e] += w * hidb[t0 + e][k];
        }
#pragma unroll
        for (int e = 0; e < 4; ++e) {
            int t = t0 + e;
            stx<F32>(out_lat, (size_t)aib[t] * LATD + o, acc[e] * cutb[t]);
        }
    }
    // ---- G1: e_s + r_s @ Wres_s  (K=64, OUT=64) ----
    {
        int o = tid & 63, g = tid >> 6;
        int t0 = g * 2;
        float acc0 = 0.f, acc1 = 0.f;
#pragma unroll 4
        for (int k = 0; k < 64; ++k) {
            float w = ldx<F32>(Wrs, k * 64 + o);
            acc0 += w * vall[t0][k];
            acc1 += w * vall[t0 + 1][k];
        }
        stx<F32>(out_edge, (size_t)(base + t0)     * DIMF + o, msvb[t0][o]     * wwb[t0][o]     + acc0);
        stx<F32>(out_edge, (size_t)(base + t0 + 1) * DIMF + o, msvb[t0 + 1][o] * wwb[t0 + 1][o] + acc1);
        // ---- G2: e_v + r_v @ Wres_v  (K=32, OUT=32, 3 comps) ----
        int o2 = tid & 31, t = tid >> 5;
        float a0 = 0.f, a1 = 0.f, a2 = 0.f;
#pragma unroll 4
        for (int v = 0; v < 32; ++v) {
            float w = ldx<F32>(Wrv, v * 32 + o2);
            a0 += w * vall[t][64 + 3*v];
            a1 += w * vall[t][64 + 3*v + 1];
            a2 += w * vall[t][64 + 3*v + 2];
        }
        float wv = wwb[t][64 + o2];
        size_t eb = (size_t)(base + t) * DIMF + 64;
        stx<F32>(out_edge, eb + 3*o2    , msvb[t][64 + 3*o2    ] * wv + a0);
        stx<F32>(out_edge, eb + 3*o2 + 1, msvb[t][64 + 3*o2 + 1] * wv + a1);
        stx<F32>(out_edge, eb + 3*o2 + 2, msvb[t][64 + 3*o2 + 2] * wv + a2);
    }
}

extern "C" void kernel_launch(void* const* d_in, const int* in_sizes, int n_in,
                              void* d_out, int out_size, void* d_ws, size_t ws_size,
                              hipStream_t stream) {
    const void* latents = d_in[0];
    const void* nodef   = d_in[1];
    const void* onehot  = d_in[2];
    const void* edgef   = d_in[3];
    const void* esh     = d_in[4];
    const int*  eidx    = (const int*)d_in[5];
    const void* cutc    = d_in[6];
    const int*  act     = (const int*)d_in[7];

    int* flag = (int*)d_ws;
    detect_kernel<<<1, 256, 0, stream>>>((const u16*)d_in[1], flag);

    const size_t EDGE_ELEMS = (size_t)N_ACT_K * DIMF;  // 32,000,000
    void* out_lat_b = (void*)((u16*)d_out + EDGE_ELEMS);
    void* out_lat_f = (void*)((float*)d_out + EDGE_ELEMS);

    // Copy latents -> latents_out (active rows overwritten by edge_kernel afterwards).
    copy_lat_kernel<0><<<(N_EDGES_K * LATD / 8) / 256, 256, 0, stream>>>(
        flag, (const uint4*)latents, (uint4*)out_lat_b, N_EDGES_K * LATD / 8);
    copy_lat_kernel<1><<<(N_EDGES_K * LATD / 4) / 256, 256, 0, stream>>>(
        flag, (const uint4*)latents, (uint4*)out_lat_f, N_EDGES_K * LATD / 4);

    edge_kernel<0><<<N_ACT_K / NE_TILE, 256, 0, stream>>>(
        flag, latents, nodef, onehot, edgef, esh, eidx, cutc, act,
        d_in[8], d_in[9], d_in[10], d_in[11], d_in[12], d_in[13], d_in[14], d_in[15],
        d_in[16], d_in[17], d_in[18], d_in[19], d_in[20], d_in[21], d_in[22], d_in[23],
        d_in[24], d_in[25], d_in[26],
        d_out, out_lat_b);
    edge_kernel<1><<<N_ACT_K / NE_TILE, 256, 0, stream>>>(
        flag, latents, nodef, onehot, edgef, esh, eidx, cutc, act,
        d_in[8], d_in[9], d_in[10], d_in[11], d_in[12], d_in[13], d_in[14], d_in[15],
        d_in[16], d_in[17], d_in[18], d_in[19], d_in[20], d_in[21], d_in[22], d_in[23],
        d_in[24], d_in[25], d_in[26],
        d_out, out_lat_f);
}